// Round 5
// baseline (2117.096 us; speedup 1.0000x reference)
//
#include <hip/hip_runtime.h>
#include <hip/hip_bf16.h>
#include <cstdint>
#include <cstddef>

namespace {

constexpr int kB = 128;
constexpr int kS = 512;
constexpr int kM = kB * kS;   // 65536 rows

typedef __hip_bfloat16 bf16;
typedef __attribute__((ext_vector_type(8))) short short8;
typedef __attribute__((ext_vector_type(4))) float f32x4;

__device__ __forceinline__ float sig_(float x) {
  return __builtin_amdgcn_rcpf(1.f + __expf(-x));
}
__device__ __forceinline__ float tanh_(float x) {
  return 1.f - 2.f * __builtin_amdgcn_rcpf(__expf(2.f * x) + 1.f);
}
__device__ __forceinline__ float b2f(bf16 h) { return __bfloat162float(h); }
__device__ __forceinline__ bf16 f2b(float f) { return __float2bfloat16(f); }

// unpack 8 bf16 (one uint4) -> 8 floats
__device__ __forceinline__ void unpack8(uint4 v, float* o) {
  o[0] = __uint_as_float(v.x << 16); o[1] = __uint_as_float(v.x & 0xffff0000u);
  o[2] = __uint_as_float(v.y << 16); o[3] = __uint_as_float(v.y & 0xffff0000u);
  o[4] = __uint_as_float(v.z << 16); o[5] = __uint_as_float(v.z & 0xffff0000u);
  o[6] = __uint_as_float(v.w << 16); o[7] = __uint_as_float(v.w & 0xffff0000u);
}
__device__ __forceinline__ void unpack4(uint2 v, float* o) {
  o[0] = __uint_as_float(v.x << 16); o[1] = __uint_as_float(v.x & 0xffff0000u);
  o[2] = __uint_as_float(v.y << 16); o[3] = __uint_as_float(v.y & 0xffff0000u);
}
__device__ __forceinline__ unsigned pack2(float a, float b) {
  bf16 ha = f2b(a), hb = f2b(b);
  return (unsigned)*(unsigned short*)&ha | ((unsigned)*(unsigned short*)&hb << 16);
}

__device__ __forceinline__ void gl_lds16(const void* g, void* l) {
  __builtin_amdgcn_global_load_lds((const __attribute__((address_space(1))) void*)g,
                                   (__attribute__((address_space(3))) void*)l, 16, 0, 0);
}

// fp32 -> bf16 weight conversion
__global__ void k_w2b(const float* __restrict__ s, bf16* __restrict__ d, int n) {
  int i = blockIdx.x * 256 + threadIdx.x;
  if (i < n) d[i] = f2b(s[i]);
}

// ---------------------------------------------------------------------------
// K1: per-tap char projection table (fp32, 372KB)
// ---------------------------------------------------------------------------
__global__ void k_table(const float* __restrict__ emb,
                        const float* __restrict__ cw3,
                        const float* __restrict__ cw5,
                        const float* __restrict__ cw7,
                        float* __restrict__ tbl) {
  int e = blockIdx.x;           // 0..15*97-1
  int tap = e / 97, ch = e % 97;
  int f = threadIdx.x;          // 0..63
  const float* w; int kk, dk;
  if (tap < 3)      { w = cw3; kk = 3; dk = tap; }
  else if (tap < 8) { w = cw5; kk = 5; dk = tap - 3; }
  else              { w = cw7; kk = 7; dk = tap - 8; }
  const float* er = emb + ch * 128;
  float s = 0.f;
  for (int c = 0; c < 128; ++c) s = fmaf(er[c], w[(f * 128 + c) * kk + dk], s);
  tbl[(size_t)e * 64 + f] = s;
}

// ---------------------------------------------------------------------------
// K2: conv via table gathers + bias + relu -> bf16 (B*S, 192)
// ---------------------------------------------------------------------------
__global__ void k_conv(const int* __restrict__ x, const float* __restrict__ tbl,
                       const float* __restrict__ cb3, const float* __restrict__ cb5,
                       const float* __restrict__ cb7, bf16* __restrict__ outA) {
  __shared__ int chs[70];
  int b = blockIdx.x >> 3;
  int s0 = (blockIdx.x & 7) << 6;
  int tid = threadIdx.x;
  if (tid < 70) {
    int g = s0 - 3 + tid;
    chs[tid] = (g >= 0 && g < kS) ? x[b * kS + g] : 0;   // char 0 => zero row
  }
  __syncthreads();
  int wv = tid >> 6;
  int f = tid & 63;
  int ntap, tap0, half; const float* cb;
  if (wv == 0)      { ntap = 3; tap0 = 0; half = 1; cb = cb3; }
  else if (wv == 1) { ntap = 5; tap0 = 3; half = 2; cb = cb5; }
  else              { ntap = 7; tap0 = 8; half = 3; cb = cb7; }
  float bias = cb[f];
  for (int p = 0; p < 64; ++p) {
    float acc = bias;
    for (int dk = 0; dk < ntap; ++dk) {
      int c = chs[p + 3 - half + dk];
      acc += tbl[(size_t)((tap0 + dk) * 97 + c) * 64 + f];
    }
    outA[(size_t)(b * kS + s0 + p) * 192 + wv * 64 + f] = f2b(fmaxf(acc, 0.f));
  }
}

// ---------------------------------------------------------------------------
// K3: highway via MFMA, fused dual GEMM (Wa and Wg in one pass).
// ---------------------------------------------------------------------------
__global__ __launch_bounds__(256) void k_hw(
    const bf16* __restrict__ A,
    const bf16* __restrict__ Wa, const float* __restrict__ Ba,
    const bf16* __restrict__ Wg, const float* __restrict__ Bg,
    bf16* __restrict__ outB) {
  __shared__ __align__(16) short As[128 * 64];
  __shared__ __align__(16) short Was[64 * 64];
  __shared__ __align__(16) short Wgs[64 * 64];
  constexpr int K = 192;
  int tid = threadIdx.x;
  int w = tid >> 6, l = tid & 63;
  int m0 = blockIdx.x * 128, n0 = blockIdx.y * 64;
  int wr = w >> 1, wc = w & 1;
  int lr = l >> 3, lc = l & 7;
  f32x4 accA[4][2], accG[4][2];
#pragma unroll
  for (int i = 0; i < 4; ++i)
#pragma unroll
    for (int j = 0; j < 2; ++j) { accA[i][j] = (f32x4)0.f; accG[i][j] = (f32x4)0.f; }

  for (int kc = 0; kc < K; kc += 64) {
    __syncthreads();
#pragma unroll
    for (int i = 0; i < 4; ++i) {
      int r = w * 32 + i * 8;
      gl_lds16(A + (size_t)(m0 + r + lr) * K + kc + lc * 8, &As[r * 64]);
    }
#pragma unroll
    for (int i = 0; i < 2; ++i) {
      int r = w * 16 + i * 8;
      gl_lds16(Wa + (size_t)(n0 + r + lr) * K + kc + lc * 8, &Was[r * 64]);
      gl_lds16(Wg + (size_t)(n0 + r + lr) * K + kc + lc * 8, &Wgs[r * 64]);
    }
    __syncthreads();
#pragma unroll
    for (int kf = 0; kf < 2; ++kf) {
      short8 af[4], ba[2], bg[2];
#pragma unroll
      for (int mt = 0; mt < 4; ++mt)
        af[mt] = *(const short8*)&As[(wr * 64 + mt * 16 + (l & 15)) * 64 + kf * 32 + (l >> 4) * 8];
#pragma unroll
      for (int nt = 0; nt < 2; ++nt) {
        int rn = (wc * 32 + nt * 16 + (l & 15)) * 64 + kf * 32 + (l >> 4) * 8;
        ba[nt] = *(const short8*)&Was[rn];
        bg[nt] = *(const short8*)&Wgs[rn];
      }
#pragma unroll
      for (int mt = 0; mt < 4; ++mt)
#pragma unroll
        for (int nt = 0; nt < 2; ++nt) {
          accA[mt][nt] = __builtin_amdgcn_mfma_f32_16x16x32_bf16(af[mt], ba[nt], accA[mt][nt], 0, 0, 0);
          accG[mt][nt] = __builtin_amdgcn_mfma_f32_16x16x32_bf16(af[mt], bg[nt], accG[mt][nt], 0, 0, 0);
        }
    }
  }
#pragma unroll
  for (int nt = 0; nt < 2; ++nt) {
    int n = n0 + wc * 32 + nt * 16 + (l & 15);
    float bav = Ba[n], bgv = Bg[n];
#pragma unroll
    for (int mt = 0; mt < 4; ++mt) {
      int mb = m0 + wr * 64 + mt * 16 + (l >> 4) * 4;
#pragma unroll
      for (int r = 0; r < 4; ++r) {
        float av = accA[mt][nt][r] + bav;
        float gv = accG[mt][nt][r] + bgv;
        float tt = sig_(gv);
        float orig = b2f(A[(size_t)(mb + r) * K + n]);
        outB[(size_t)(mb + r) * K + n] = f2b(tt * fmaxf(av, 0.f) + (1.f - tt) * orig);
      }
    }
  }
}

// ---------------------------------------------------------------------------
// K4: LSTM input projection via MFMA. BM=128, BN=128, BK=64, 4 waves 2x2.
// xg written TIME-MAJOR: xg[(t*128 + seq)*1024 + col]  (col: dir*512+gate*128+u)
// ---------------------------------------------------------------------------
__global__ __launch_bounds__(256) void k_pgemm(
    const bf16* __restrict__ A, int K,
    const bf16* __restrict__ W,
    const float* __restrict__ bfw, const float* __restrict__ bbw,
    bf16* __restrict__ xg) {
  __shared__ __align__(16) short As[128 * 64];
  __shared__ __align__(16) short Bs[128 * 64];
  int tid = threadIdx.x;
  int w = tid >> 6, l = tid & 63;
  int m0 = blockIdx.x * 128, n0 = blockIdx.y * 128;
  int wr = w >> 1, wc = w & 1;
  int lr = l >> 3, lc = l & 7;
  f32x4 acc[4][4];
#pragma unroll
  for (int i = 0; i < 4; ++i)
#pragma unroll
    for (int j = 0; j < 4; ++j) acc[i][j] = (f32x4)0.f;

  for (int kc = 0; kc < K; kc += 64) {
    __syncthreads();
#pragma unroll
    for (int i = 0; i < 4; ++i) {
      int r = w * 32 + i * 8;
      gl_lds16(A + (size_t)(m0 + r + lr) * K + kc + lc * 8, &As[r * 64]);
      gl_lds16(W + (size_t)(n0 + r + lr) * K + kc + lc * 8, &Bs[r * 64]);
    }
    __syncthreads();
#pragma unroll
    for (int kf = 0; kf < 2; ++kf) {
      short8 af[4], bfr[4];
#pragma unroll
      for (int mt = 0; mt < 4; ++mt)
        af[mt] = *(const short8*)&As[(wr * 64 + mt * 16 + (l & 15)) * 64 + kf * 32 + (l >> 4) * 8];
#pragma unroll
      for (int nt = 0; nt < 4; ++nt)
        bfr[nt] = *(const short8*)&Bs[(wc * 64 + nt * 16 + (l & 15)) * 64 + kf * 32 + (l >> 4) * 8];
#pragma unroll
      for (int mt = 0; mt < 4; ++mt)
#pragma unroll
        for (int nt = 0; nt < 4; ++nt)
          acc[mt][nt] = __builtin_amdgcn_mfma_f32_16x16x32_bf16(af[mt], bfr[nt], acc[mt][nt], 0, 0, 0);
    }
  }
#pragma unroll
  for (int nt = 0; nt < 4; ++nt) {
    int n = n0 + wc * 64 + nt * 16 + (l & 15);
    float bv = (n < 512) ? bfw[n] : bbw[n - 512];
#pragma unroll
    for (int mt = 0; mt < 4; ++mt) {
      int mb = m0 + wr * 64 + mt * 16 + (l >> 4) * 4;
#pragma unroll
      for (int r = 0; r < 4; ++r) {
        int row = mb + r;                                  // seq-major: seq*512+t
        int rp = ((row & 511) << 7) | (row >> 9);          // time-major: t*128+seq
        xg[((size_t)rp << 10) + n] = f2b(acc[mt][nt][r] + bv);
      }
    }
  }
}

// ---------------------------------------------------------------------------
// K5: LSTM recurrence as per-step batched MFMA GEMM.
// Grid 16 = (dir 0..1) x (8 groups of 16 seqs). 256 threads = 4 waves.
// Per step: Z[512x16] = whh[512x128] @ H_T[16x128]^T via MFMA; whh in VGPRs.
// Wave w owns u in [w*32, w*32+32): M-tiles g*128 + w*32 + tl*16 -> zi/zf/zg/zo
// for the same u sit in the same lane (different acc regs) -> in-register gates.
// H_T double-buffered in LDS [16][136] bf16 (pad 136 -> <=2-way banks).
// xg is time-major; prefetched one step ahead into a second register set.
// ---------------------------------------------------------------------------
__global__ __launch_bounds__(256, 1) void k_rec2(
    const bf16* __restrict__ xg,
    const bf16* __restrict__ whhF, const bf16* __restrict__ whhB,
    bf16* __restrict__ out) {
  int blk = blockIdx.x;
  int dir = blk >> 3;
  int seq0 = (blk & 7) * 16;
  const short* whhs = (const short*)(dir ? whhB : whhF);
  const bool rev = (dir == 1);
  int tid = threadIdx.x;
  int w = tid >> 6, l = tid & 63;
  int ln = l & 15;               // seq offset / MFMA N-col
  int lk = l >> 4;               // 0..3
  int u0base = w * 32 + lk * 4;  // + tl*16

  // whh fragments in registers: wf[g][tl][kk], M row = g*128+w*32+tl*16+ln
  short8 wf[4][2][4];
#pragma unroll
  for (int g = 0; g < 4; ++g)
#pragma unroll
    for (int tl = 0; tl < 2; ++tl)
#pragma unroll
      for (int kk = 0; kk < 4; ++kk)
        wf[g][tl][kk] = *(const short8*)&whhs[(size_t)(g * 128 + w * 32 + tl * 16 + ln) * 128 + kk * 32 + lk * 8];

  __shared__ __align__(16) short HT[2][16][136];
  for (int i = tid; i < 16 * 136; i += 256) ((short*)HT)[i] = 0;  // zero HT[0]

  float cst[2][4];
#pragma unroll
  for (int tl = 0; tl < 2; ++tl)
#pragma unroll
    for (int r = 0; r < 4; ++r) cst[tl][r] = 0.f;

  const size_t cbase = (size_t)(seq0 + ln) * 1024 + dir * 512;
  const size_t obase0 = ((size_t)(seq0 + ln)) * 131072 + (size_t)dir * 128;

  uint2 xqA[4][2], xqB[4][2];
  {
    int tt0 = rev ? 511 : 0;
    const bf16* xb = xg + (((size_t)tt0) << 17) + cbase;
#pragma unroll
    for (int g = 0; g < 4; ++g)
#pragma unroll
      for (int tl = 0; tl < 2; ++tl)
        xqA[g][tl] = *(const uint2*)(xb + g * 128 + u0base + tl * 16);
  }
  __syncthreads();

  auto step = [&](int tt, int ttp, const short* RB, short* WB,
                  uint2 (&xu)[4][2], uint2 (&xp)[4][2]) {
    // B-fragments from H_T (broadcast to all waves)
    short8 bfr[4];
#pragma unroll
    for (int kk = 0; kk < 4; ++kk)
      bfr[kk] = *(const short8*)&RB[ln * 136 + kk * 32 + lk * 8];
    // prefetch xg for step ttp
    const bf16* xb = xg + (((size_t)ttp) << 17) + cbase;
#pragma unroll
    for (int g = 0; g < 4; ++g)
#pragma unroll
      for (int tl = 0; tl < 2; ++tl)
        xp[g][tl] = *(const uint2*)(xb + g * 128 + u0base + tl * 16);
    // Z = whh @ h
    f32x4 acc[4][2];
#pragma unroll
    for (int g = 0; g < 4; ++g) { acc[g][0] = (f32x4)0.f; acc[g][1] = (f32x4)0.f; }
#pragma unroll
    for (int kk = 0; kk < 4; ++kk)
#pragma unroll
      for (int g = 0; g < 4; ++g)
#pragma unroll
        for (int tl = 0; tl < 2; ++tl)
          acc[g][tl] = __builtin_amdgcn_mfma_f32_16x16x32_bf16(wf[g][tl][kk], bfr[kk], acc[g][tl], 0, 0, 0);
    // gates, fully in-register
    size_t ob = obase0 + (size_t)tt * 256;
#pragma unroll
    for (int tl = 0; tl < 2; ++tl) {
      float xi[4], xff[4], xgg[4], xoo[4];
      unpack4(xu[0][tl], xi);  unpack4(xu[1][tl], xff);
      unpack4(xu[2][tl], xgg); unpack4(xu[3][tl], xoo);
      float hv[4];
#pragma unroll
      for (int r = 0; r < 4; ++r) {
        float zi = acc[0][tl][r] + xi[r];
        float zf = acc[1][tl][r] + xff[r];
        float zg = acc[2][tl][r] + xgg[r];
        float zo = acc[3][tl][r] + xoo[r];
        float ig = sig_(zi), fg = sig_(zf), gv = tanh_(zg), og = sig_(zo);
        float cc = fmaf(fg, cst[tl][r], ig * gv);
        cst[tl][r] = cc;
        hv[r] = og * tanh_(cc);
      }
      uint2 hp;
      hp.x = pack2(hv[0], hv[1]);
      hp.y = pack2(hv[2], hv[3]);
      *(uint2*)&WB[ln * 136 + u0base + tl * 16] = hp;            // h -> H_T[nxt]
      *(uint2*)(out + ob + u0base + tl * 16) = hp;               // h -> global
    }
  };

  for (int t = 0; t < kS; t += 2) {
    int tt0 = rev ? 511 - t : t;
    int tt1 = rev ? 510 - t : t + 1;
    int tp2 = (t + 2 < kS) ? t + 2 : kS - 1;
    int tt2 = rev ? 511 - tp2 : tp2;
    step(tt0, tt1, &HT[0][0][0], &HT[1][0][0], xqA, xqB);
    __syncthreads();
    step(tt1, tt2, &HT[1][0][0], &HT[0][0][0], xqB, xqA);
    __syncthreads();
  }
}

// ---------------------------------------------------------------------------
// K6: classifier + char mask. out1 bf16 -> em fp32 (or NEG)
// ---------------------------------------------------------------------------
__global__ __launch_bounds__(256) void k_cls(
    const bf16* __restrict__ out1, const float* __restrict__ cls_w,
    const float* __restrict__ cls_b, const int* __restrict__ x,
    float* __restrict__ em) {
  __shared__ float W[17 * 256];
  __shared__ float part[64 * 4 * 17];
  int tid = threadIdx.x;
  for (int i = tid; i < 17 * 256; i += 256) W[i] = cls_w[i];
  __syncthreads();
  int r = tid >> 2, q = tid & 3;
  size_t row = (size_t)blockIdx.x * 64 + r;
  float acc[17];
#pragma unroll
  for (int j = 0; j < 17; ++j) acc[j] = 0.f;
  const uint4* a4p = (const uint4*)(out1 + row * 256 + q * 64);
  for (int i = 0; i < 8; ++i) {
    float f8[8]; unpack8(a4p[i], f8);
#pragma unroll
    for (int j = 0; j < 17; ++j) {
      const float* wr = &W[j * 256 + q * 64 + i * 8];
#pragma unroll
      for (int e = 0; e < 8; ++e) acc[j] = fmaf(f8[e], wr[e], acc[j]);
    }
  }
#pragma unroll
  for (int j = 0; j < 17; ++j) part[(r * 4 + q) * 17 + j] = acc[j];
  __syncthreads();
  for (int idx = tid; idx < 64 * 17; idx += 256) {
    int rr = idx / 17, j = idx % 17;
    size_t row2 = (size_t)blockIdx.x * 64 + rr;
    float v = part[(rr * 4 + 0) * 17 + j] + part[(rr * 4 + 1) * 17 + j] +
              part[(rr * 4 + 2) * 17 + j] + part[(rr * 4 + 3) * 17 + j] + cls_b[j];
    em[row2 * 17 + j] = (x[row2] != 0) ? v : -1e9f;
  }
}

// ---------------------------------------------------------------------------
// K7: CRF loss per sequence (1 wave / block). res[b] = logZ - score
// ---------------------------------------------------------------------------
__global__ __launch_bounds__(64) void k_crf(
    const float* __restrict__ em, const int* __restrict__ tags,
    const float* __restrict__ mask, const float* __restrict__ trans,
    const float* __restrict__ start_t, const float* __restrict__ end_t,
    float* __restrict__ res) {
  int b = blockIdx.x;
  int lane = threadIdx.x;
  const float* emB = em + (size_t)b * kS * 17;
  const int* tg = tags + b * kS;
  const float* mk = mask + b * kS;

  float tcol[17];
  if (lane < 17) {
#pragma unroll
    for (int i = 0; i < 17; ++i) tcol[i] = trans[i * 17 + lane];
  }
  float sc = 0.f, msum = 0.f;
  for (int t = lane; t < kS; t += 64) msum += mk[t];
  for (int t = 1 + lane; t < kS; t += 64)
    sc += (trans[tg[t - 1] * 17 + tg[t]] + emB[(size_t)t * 17 + tg[t]]) * mk[t];
#pragma unroll
  for (int o = 32; o; o >>= 1) { sc += __shfl_xor(sc, o); msum += __shfl_xor(msum, o); }

  __shared__ float al[17];
  if (lane < 17) al[lane] = start_t[lane] + emB[lane];
  __syncthreads();
  for (int t = 1; t < kS; ++t) {
    float nxt = 0.f;
    if (lane < 17) {
      float v[17]; float mx = -3.4e38f;
#pragma unroll
      for (int i = 0; i < 17; ++i) { v[i] = al[i] + tcol[i]; mx = fmaxf(mx, v[i]); }
      float s = 0.f;
#pragma unroll
      for (int i = 0; i < 17; ++i) s += __expf(v[i] - mx);
      float m = mk[t];
      nxt = (mx + __logf(s) + emB[(size_t)t * 17 + lane]) * m + al[lane] * (1.f - m);
    }
    __syncthreads();
    if (lane < 17) al[lane] = nxt;
    __syncthreads();
  }
  float val = (lane < 17) ? al[lane] + end_t[lane] : -3.4e38f;
  float mx = val;
#pragma unroll
  for (int o = 32; o; o >>= 1) mx = fmaxf(mx, __shfl_xor(mx, o));
  float s = (lane < 17) ? __expf(val - mx) : 0.f;
#pragma unroll
  for (int o = 32; o; o >>= 1) s += __shfl_xor(s, o);
  float logZ = mx + __logf(s);
  if (lane == 0) {
    float score = sc + start_t[tg[0]] + emB[tg[0]];
    int last_real = (int)(msum + 0.5f) - 1;
    if (last_real >= 0) score += end_t[tg[last_real]];
    res[b] = logZ - score;
  }
}

// K8: deterministic mean over 128 sequences -> d_out[0]
__global__ void k_loss(const float* __restrict__ res, float* __restrict__ out) {
  __shared__ float s[128];
  int tid = threadIdx.x;
  s[tid] = res[tid];
  __syncthreads();
  for (int off = 64; off; off >>= 1) {
    if (tid < off) s[tid] += s[tid + off];
    __syncthreads();
  }
  if (tid == 0) out[0] = s[0] / 128.f;
}

}  // namespace

extern "C" void kernel_launch(void* const* d_in, const int* in_sizes, int n_in,
                              void* d_out, int out_size, void* d_ws, size_t ws_size,
                              hipStream_t stream) {
  (void)in_sizes; (void)n_in; (void)out_size; (void)ws_size;
  const int*   x       = (const int*)  d_in[0];
  const int*   tags    = (const int*)  d_in[1];
  const float* mask    = (const float*)d_in[2];
  const float* emb     = (const float*)d_in[3];
  const float* cw3     = (const float*)d_in[4];
  const float* cb3     = (const float*)d_in[5];
  const float* cw5     = (const float*)d_in[6];
  const float* cb5     = (const float*)d_in[7];
  const float* cw7     = (const float*)d_in[8];
  const float* cb7     = (const float*)d_in[9];
  const float* hw_w    = (const float*)d_in[10];
  const float* hw_b    = (const float*)d_in[11];
  const float* hwg_w   = (const float*)d_in[12];
  const float* hwg_b   = (const float*)d_in[13];
  const float* wih0f   = (const float*)d_in[14];
  const float* whh0f   = (const float*)d_in[15];
  const float* b0f     = (const float*)d_in[16];
  const float* wih0b   = (const float*)d_in[17];
  const float* whh0b   = (const float*)d_in[18];
  const float* b0b     = (const float*)d_in[19];
  const float* wih1f   = (const float*)d_in[20];
  const float* whh1f   = (const float*)d_in[21];
  const float* b1f     = (const float*)d_in[22];
  const float* wih1b   = (const float*)d_in[23];
  const float* whh1b   = (const float*)d_in[24];
  const float* b1b     = (const float*)d_in[25];
  const float* cls_w   = (const float*)d_in[26];
  const float* cls_b   = (const float*)d_in[27];
  const float* trans   = (const float*)d_in[28];
  const float* start_t = (const float*)d_in[29];
  const float* end_t   = (const float*)d_in[30];

  // Workspace layout. tbl fp32 | bf16 weights | bf16 activations. ~210 MB.
  char* ws = (char*)d_ws;
  const size_t OFF_W0 = 393216;                            // tbl is [0, 372KB)
  const size_t OFF_W1 = OFF_W0 + (size_t)1024 * 192 * 2;
  const size_t OFF_WA = OFF_W1 + (size_t)1024 * 256 * 2;
  const size_t OFF_WG = OFF_WA + (size_t)192 * 192 * 2;
  const size_t OFF_WH = OFF_WG + (size_t)192 * 192 * 2;    // 4x whh bf16 (512KB)
  const size_t OFF_A  = OFF_WH + (size_t)4 * 512 * 128 * 2;
  const size_t SZ_A   = (size_t)kM * 192 * 2;              // 24 MB
  const size_t OFF_B  = OFF_A + SZ_A;
  const size_t OFF_O0 = OFF_B + SZ_A;                      // out0 bf16 (32MB); em fp32 later
  const size_t OFF_XG = OFF_O0 + (size_t)kM * 256 * 2;     // xg bf16 dual (128MB)
  float* tbl  = (float*)ws;
  bf16*  W0b  = (bf16*)(ws + OFF_W0);
  bf16*  W1b  = (bf16*)(ws + OFF_W1);
  bf16*  WAb  = (bf16*)(ws + OFF_WA);
  bf16*  WGb  = (bf16*)(ws + OFF_WG);
  bf16*  WHb  = (bf16*)(ws + OFF_WH);
  bf16*  bufA = (bf16*)(ws + OFF_A);
  bf16*  bufB = (bf16*)(ws + OFF_B);
  bf16*  out0 = (bf16*)(ws + OFF_O0);
  bf16*  out1 = (bf16*)(ws + OFF_A);                       // bufA/bufB dead by rec1
  bf16*  xg   = (bf16*)(ws + OFF_XG);
  float* em   = (float*)(ws + OFF_O0);                     // out0 dead after proj1
  float* resv = (float*)(ws + OFF_O0 + (size_t)kM * 17 * 4);

  // weight conversion prepass
  k_w2b<<<384, 256, 0, stream>>>(wih0f, W0b, 512 * 192);
  k_w2b<<<384, 256, 0, stream>>>(wih0b, W0b + 512 * 192, 512 * 192);
  k_w2b<<<512, 256, 0, stream>>>(wih1f, W1b, 512 * 256);
  k_w2b<<<512, 256, 0, stream>>>(wih1b, W1b + 512 * 256, 512 * 256);
  k_w2b<<<144, 256, 0, stream>>>(hw_w, WAb, 192 * 192);
  k_w2b<<<144, 256, 0, stream>>>(hwg_w, WGb, 192 * 192);
  k_w2b<<<256, 256, 0, stream>>>(whh0f, WHb + 0 * 65536, 512 * 128);
  k_w2b<<<256, 256, 0, stream>>>(whh0b, WHb + 1 * 65536, 512 * 128);
  k_w2b<<<256, 256, 0, stream>>>(whh1f, WHb + 2 * 65536, 512 * 128);
  k_w2b<<<256, 256, 0, stream>>>(whh1b, WHb + 3 * 65536, 512 * 128);

  k_table<<<15 * 97, 64, 0, stream>>>(emb, cw3, cw5, cw7, tbl);
  k_conv<<<kB * (kS / 64), 192, 0, stream>>>(x, tbl, cb3, cb5, cb7, bufA);
  k_hw<<<dim3(kM / 128, 3), 256, 0, stream>>>(bufA, WAb, hw_b, WGb, hwg_b, bufB);

  k_pgemm<<<dim3(kM / 128, 8), 256, 0, stream>>>(bufB, 192, W0b, b0f, b0b, xg);
  k_rec2<<<16, 256, 0, stream>>>(xg, WHb + 0 * 65536, WHb + 1 * 65536, out0);
  k_pgemm<<<dim3(kM / 128, 8), 256, 0, stream>>>(out0, 256, W1b, b1f, b1b, xg);
  k_rec2<<<16, 256, 0, stream>>>(xg, WHb + 2 * 65536, WHb + 3 * 65536, out1);

  k_cls<<<kM / 64, 256, 0, stream>>>(out1, cls_w, cls_b, x, em);
  k_crf<<<kB, 64, 0, stream>>>(em, tags, mask, trans, start_t, end_t, resv);
  k_loss<<<1, 128, 0, stream>>>(resv, (float*)d_out);
}

// Round 6
// 1270.860 us; speedup vs baseline: 1.6659x; 1.6659x over previous
//
#include <hip/hip_runtime.h>
#include <hip/hip_bf16.h>
#include <cstdint>
#include <cstddef>

namespace {

constexpr int kB = 128;
constexpr int kS = 512;
constexpr int kM = kB * kS;   // 65536 rows

typedef __hip_bfloat16 bf16;
typedef __attribute__((ext_vector_type(8))) short short8;
typedef __attribute__((ext_vector_type(4))) float f32x4;

__device__ __forceinline__ float sig_(float x) {
  return __builtin_amdgcn_rcpf(1.f + __expf(-x));
}
__device__ __forceinline__ float tanh_(float x) {
  return 1.f - 2.f * __builtin_amdgcn_rcpf(__expf(2.f * x) + 1.f);
}
__device__ __forceinline__ float b2f(bf16 h) { return __bfloat162float(h); }
__device__ __forceinline__ bf16 f2b(float f) { return __float2bfloat16(f); }

// unpack 8 bf16 (one uint4) -> 8 floats
__device__ __forceinline__ void unpack8(uint4 v, float* o) {
  o[0] = __uint_as_float(v.x << 16); o[1] = __uint_as_float(v.x & 0xffff0000u);
  o[2] = __uint_as_float(v.y << 16); o[3] = __uint_as_float(v.y & 0xffff0000u);
  o[4] = __uint_as_float(v.z << 16); o[5] = __uint_as_float(v.z & 0xffff0000u);
  o[6] = __uint_as_float(v.w << 16); o[7] = __uint_as_float(v.w & 0xffff0000u);
}
__device__ __forceinline__ unsigned pack2(float a, float b) {
  bf16 ha = f2b(a), hb = f2b(b);
  return (unsigned)*(unsigned short*)&ha | ((unsigned)*(unsigned short*)&hb << 16);
}

__device__ __forceinline__ void gl_lds16(const void* g, void* l) {
  __builtin_amdgcn_global_load_lds((const __attribute__((address_space(1))) void*)g,
                                   (__attribute__((address_space(3))) void*)l, 16, 0, 0);
}

// fp32 -> bf16 weight conversion
__global__ void k_w2b(const float* __restrict__ s, bf16* __restrict__ d, int n) {
  int i = blockIdx.x * 256 + threadIdx.x;
  if (i < n) d[i] = f2b(s[i]);
}

// ---------------------------------------------------------------------------
// K1: per-tap char projection table (fp32, 372KB)
// ---------------------------------------------------------------------------
__global__ void k_table(const float* __restrict__ emb,
                        const float* __restrict__ cw3,
                        const float* __restrict__ cw5,
                        const float* __restrict__ cw7,
                        float* __restrict__ tbl) {
  int e = blockIdx.x;           // 0..15*97-1
  int tap = e / 97, ch = e % 97;
  int f = threadIdx.x;          // 0..63
  const float* w; int kk, dk;
  if (tap < 3)      { w = cw3; kk = 3; dk = tap; }
  else if (tap < 8) { w = cw5; kk = 5; dk = tap - 3; }
  else              { w = cw7; kk = 7; dk = tap - 8; }
  const float* er = emb + ch * 128;
  float s = 0.f;
  for (int c = 0; c < 128; ++c) s = fmaf(er[c], w[(f * 128 + c) * kk + dk], s);
  tbl[(size_t)e * 64 + f] = s;
}

// ---------------------------------------------------------------------------
// K2: conv via table gathers + bias + relu -> bf16 (B*S, 192)
// ---------------------------------------------------------------------------
__global__ void k_conv(const int* __restrict__ x, const float* __restrict__ tbl,
                       const float* __restrict__ cb3, const float* __restrict__ cb5,
                       const float* __restrict__ cb7, bf16* __restrict__ outA) {
  __shared__ int chs[70];
  int b = blockIdx.x >> 3;
  int s0 = (blockIdx.x & 7) << 6;
  int tid = threadIdx.x;
  if (tid < 70) {
    int g = s0 - 3 + tid;
    chs[tid] = (g >= 0 && g < kS) ? x[b * kS + g] : 0;   // char 0 => zero row
  }
  __syncthreads();
  int wv = tid >> 6;
  int f = tid & 63;
  int ntap, tap0, half; const float* cb;
  if (wv == 0)      { ntap = 3; tap0 = 0; half = 1; cb = cb3; }
  else if (wv == 1) { ntap = 5; tap0 = 3; half = 2; cb = cb5; }
  else              { ntap = 7; tap0 = 8; half = 3; cb = cb7; }
  float bias = cb[f];
  for (int p = 0; p < 64; ++p) {
    float acc = bias;
    for (int dk = 0; dk < ntap; ++dk) {
      int c = chs[p + 3 - half + dk];
      acc += tbl[(size_t)((tap0 + dk) * 97 + c) * 64 + f];
    }
    outA[(size_t)(b * kS + s0 + p) * 192 + wv * 64 + f] = f2b(fmaxf(acc, 0.f));
  }
}

// ---------------------------------------------------------------------------
// K3: highway via MFMA, fused dual GEMM (Wa and Wg in one pass).
// ---------------------------------------------------------------------------
__global__ __launch_bounds__(256) void k_hw(
    const bf16* __restrict__ A,
    const bf16* __restrict__ Wa, const float* __restrict__ Ba,
    const bf16* __restrict__ Wg, const float* __restrict__ Bg,
    bf16* __restrict__ outB) {
  __shared__ __align__(16) short As[128 * 64];
  __shared__ __align__(16) short Was[64 * 64];
  __shared__ __align__(16) short Wgs[64 * 64];
  constexpr int K = 192;
  int tid = threadIdx.x;
  int w = tid >> 6, l = tid & 63;
  int m0 = blockIdx.x * 128, n0 = blockIdx.y * 64;
  int wr = w >> 1, wc = w & 1;
  int lr = l >> 3, lc = l & 7;
  f32x4 accA[4][2], accG[4][2];
#pragma unroll
  for (int i = 0; i < 4; ++i)
#pragma unroll
    for (int j = 0; j < 2; ++j) { accA[i][j] = (f32x4)0.f; accG[i][j] = (f32x4)0.f; }

  for (int kc = 0; kc < K; kc += 64) {
    __syncthreads();
#pragma unroll
    for (int i = 0; i < 4; ++i) {
      int r = w * 32 + i * 8;
      gl_lds16(A + (size_t)(m0 + r + lr) * K + kc + lc * 8, &As[r * 64]);
    }
#pragma unroll
    for (int i = 0; i < 2; ++i) {
      int r = w * 16 + i * 8;
      gl_lds16(Wa + (size_t)(n0 + r + lr) * K + kc + lc * 8, &Was[r * 64]);
      gl_lds16(Wg + (size_t)(n0 + r + lr) * K + kc + lc * 8, &Wgs[r * 64]);
    }
    __syncthreads();
#pragma unroll
    for (int kf = 0; kf < 2; ++kf) {
      short8 af[4], ba[2], bg[2];
#pragma unroll
      for (int mt = 0; mt < 4; ++mt)
        af[mt] = *(const short8*)&As[(wr * 64 + mt * 16 + (l & 15)) * 64 + kf * 32 + (l >> 4) * 8];
#pragma unroll
      for (int nt = 0; nt < 2; ++nt) {
        int rn = (wc * 32 + nt * 16 + (l & 15)) * 64 + kf * 32 + (l >> 4) * 8;
        ba[nt] = *(const short8*)&Was[rn];
        bg[nt] = *(const short8*)&Wgs[rn];
      }
#pragma unroll
      for (int mt = 0; mt < 4; ++mt)
#pragma unroll
        for (int nt = 0; nt < 2; ++nt) {
          accA[mt][nt] = __builtin_amdgcn_mfma_f32_16x16x32_bf16(af[mt], ba[nt], accA[mt][nt], 0, 0, 0);
          accG[mt][nt] = __builtin_amdgcn_mfma_f32_16x16x32_bf16(af[mt], bg[nt], accG[mt][nt], 0, 0, 0);
        }
    }
  }
#pragma unroll
  for (int nt = 0; nt < 2; ++nt) {
    int n = n0 + wc * 32 + nt * 16 + (l & 15);
    float bav = Ba[n], bgv = Bg[n];
#pragma unroll
    for (int mt = 0; mt < 4; ++mt) {
      int mb = m0 + wr * 64 + mt * 16 + (l >> 4) * 4;
#pragma unroll
      for (int r = 0; r < 4; ++r) {
        float av = accA[mt][nt][r] + bav;
        float gv = accG[mt][nt][r] + bgv;
        float tt = sig_(gv);
        float orig = b2f(A[(size_t)(mb + r) * K + n]);
        outB[(size_t)(mb + r) * K + n] = f2b(tt * fmaxf(av, 0.f) + (1.f - tt) * orig);
      }
    }
  }
}

// ---------------------------------------------------------------------------
// K4: LSTM input projection via MFMA. BM=128, BN=128, BK=64, 4 waves 2x2.
// xg written TIME-MAJOR: xg[(t*128 + seq)*1024 + col]  (col: dir*512+gate*128+u)
// ---------------------------------------------------------------------------
__global__ __launch_bounds__(256) void k_pgemm(
    const bf16* __restrict__ A, int K,
    const bf16* __restrict__ W,
    const float* __restrict__ bfw, const float* __restrict__ bbw,
    bf16* __restrict__ xg) {
  __shared__ __align__(16) short As[128 * 64];
  __shared__ __align__(16) short Bs[128 * 64];
  int tid = threadIdx.x;
  int w = tid >> 6, l = tid & 63;
  int m0 = blockIdx.x * 128, n0 = blockIdx.y * 128;
  int wr = w >> 1, wc = w & 1;
  int lr = l >> 3, lc = l & 7;
  f32x4 acc[4][4];
#pragma unroll
  for (int i = 0; i < 4; ++i)
#pragma unroll
    for (int j = 0; j < 4; ++j) acc[i][j] = (f32x4)0.f;

  for (int kc = 0; kc < K; kc += 64) {
    __syncthreads();
#pragma unroll
    for (int i = 0; i < 4; ++i) {
      int r = w * 32 + i * 8;
      gl_lds16(A + (size_t)(m0 + r + lr) * K + kc + lc * 8, &As[r * 64]);
      gl_lds16(W + (size_t)(n0 + r + lr) * K + kc + lc * 8, &Bs[r * 64]);
    }
    __syncthreads();
#pragma unroll
    for (int kf = 0; kf < 2; ++kf) {
      short8 af[4], bfr[4];
#pragma unroll
      for (int mt = 0; mt < 4; ++mt)
        af[mt] = *(const short8*)&As[(wr * 64 + mt * 16 + (l & 15)) * 64 + kf * 32 + (l >> 4) * 8];
#pragma unroll
      for (int nt = 0; nt < 4; ++nt)
        bfr[nt] = *(const short8*)&Bs[(wc * 64 + nt * 16 + (l & 15)) * 64 + kf * 32 + (l >> 4) * 8];
#pragma unroll
      for (int mt = 0; mt < 4; ++mt)
#pragma unroll
        for (int nt = 0; nt < 4; ++nt)
          acc[mt][nt] = __builtin_amdgcn_mfma_f32_16x16x32_bf16(af[mt], bfr[nt], acc[mt][nt], 0, 0, 0);
    }
  }
#pragma unroll
  for (int nt = 0; nt < 4; ++nt) {
    int n = n0 + wc * 64 + nt * 16 + (l & 15);
    float bv = (n < 512) ? bfw[n] : bbw[n - 512];
#pragma unroll
    for (int mt = 0; mt < 4; ++mt) {
      int mb = m0 + wr * 64 + mt * 16 + (l >> 4) * 4;
#pragma unroll
      for (int r = 0; r < 4; ++r) {
        int row = mb + r;                                  // seq-major: seq*512+t
        int rp = ((row & 511) << 7) | (row >> 9);          // time-major: t*128+seq
        xg[((size_t)rp << 10) + n] = f2b(acc[mt][nt][r] + bv);
      }
    }
  }
}

// ---------------------------------------------------------------------------
// K5: LSTM recurrence as per-step batched MFMA GEMM.  v2.
// Grid 32 = (dir 0..1) x (16 groups of 8 seqs). 512 threads = 8 waves (2/SIMD).
// Wave w owns u-chunk [w*16, w*16+16) for ALL 4 gates (4 M-tiles, 16 MFMA/step),
// weights = 16 short8 = 64 VGPR/lane. MFMA N-cols 0..7 = seqs, 8..15 read
// permanently-zero HT rows. After MFMA, shfl_xor(8) moves acc rows {2,3} to the
// upper-half lanes so each lane computes exactly 2 valid LSTM cells
// (seq = seq0+(ln&7), u = w*16+lk*4 + (ln>=8 ? 2 : 0) + {0,1}).
// HT double-buffered [2][16][136] bf16; one barrier per step; xg prefetch
// distance 2 (loads overwrite the consuming register set after copy-out).
// ---------------------------------------------------------------------------
__global__ __launch_bounds__(512, 2) void k_rec2(
    const bf16* __restrict__ xg,
    const bf16* __restrict__ whhF, const bf16* __restrict__ whhB,
    bf16* __restrict__ out) {
  int blk = blockIdx.x;
  int dir = blk >> 4;
  int seq0 = (blk & 15) * 8;
  const short* whhs = (const short*)(dir ? whhB : whhF);
  const bool rev = (dir == 1);
  int tid = threadIdx.x;
  int w = tid >> 6, l = tid & 63;
  int ln = l & 15, lk = l >> 4;
  bool hi = (ln >= 8);
  int sLoc = ln & 7;
  int seq = seq0 + sLoc;
  int up = w * 16 + lk * 4 + (hi ? 2 : 0);   // my 2 u's: up, up+1

  // whh A-fragments in registers: wf[g][kk], row = g*128 + w*16 + ln
  short8 wf[4][4];
#pragma unroll
  for (int g = 0; g < 4; ++g)
#pragma unroll
    for (int kk = 0; kk < 4; ++kk)
      wf[g][kk] = *(const short8*)&whhs[(size_t)(g * 128 + w * 16 + ln) * 128 + kk * 32 + lk * 8];

  __shared__ __align__(16) short HT[2][16][136];
  for (int i = tid; i < 2 * 16 * 136; i += 512) ((short*)HT)[i] = 0;

  float c0 = 0.f, c1 = 0.f;

  const bf16* xbase = xg + (size_t)seq * 1024 + dir * 512 + up;
  bf16* obase = out + (size_t)seq * 131072 + (size_t)dir * 128 + up;

  uint xA[4], xB[4];
  {
    int p0 = rev ? 511 : 0, p1 = rev ? 510 : 1;
    const bf16* xb0 = xbase + ((size_t)p0 << 17);
    const bf16* xb1 = xbase + ((size_t)p1 << 17);
#pragma unroll
    for (int g = 0; g < 4; ++g) {
      xA[g] = *(const uint*)(xb0 + g * 128);
      xB[g] = *(const uint*)(xb1 + g * 128);
    }
  }
  __syncthreads();

  auto do_step = [&](int tphys, int tpref, const short* RB, short* WB, uint (&x)[4]) {
    // B-fragments from HT (rows 8..15 are zero)
    short8 b0 = *(const short8*)&RB[ln * 136 + 0  + lk * 8];
    short8 b1 = *(const short8*)&RB[ln * 136 + 32 + lk * 8];
    short8 b2 = *(const short8*)&RB[ln * 136 + 64 + lk * 8];
    short8 b3 = *(const short8*)&RB[ln * 136 + 96 + lk * 8];
    // save current xg regs, then overwrite with prefetch for t+2
    uint xc[4];
#pragma unroll
    for (int g = 0; g < 4; ++g) xc[g] = x[g];
    {
      const bf16* xb = xbase + ((size_t)tpref << 17);
#pragma unroll
      for (int g = 0; g < 4; ++g) x[g] = *(const uint*)(xb + g * 128);
    }
    // Z = whh @ h : 16 MFMAs
    f32x4 a[4];
#pragma unroll
    for (int g = 0; g < 4; ++g) a[g] = (f32x4)0.f;
#pragma unroll
    for (int g = 0; g < 4; ++g) a[g] = __builtin_amdgcn_mfma_f32_16x16x32_bf16(wf[g][0], b0, a[g], 0, 0, 0);
#pragma unroll
    for (int g = 0; g < 4; ++g) a[g] = __builtin_amdgcn_mfma_f32_16x16x32_bf16(wf[g][1], b1, a[g], 0, 0, 0);
#pragma unroll
    for (int g = 0; g < 4; ++g) a[g] = __builtin_amdgcn_mfma_f32_16x16x32_bf16(wf[g][2], b2, a[g], 0, 0, 0);
#pragma unroll
    for (int g = 0; g < 4; ++g) a[g] = __builtin_amdgcn_mfma_f32_16x16x32_bf16(wf[g][3], b3, a[g], 0, 0, 0);
    // redistribute rows {2,3} to upper-half lanes; every lane -> 2 valid cells
    float zr0[4], zr1[4];
#pragma unroll
    for (int g = 0; g < 4; ++g) {
      float t2 = __shfl_xor(a[g][2], 8);
      float t3 = __shfl_xor(a[g][3], 8);
      zr0[g] = hi ? t2 : a[g][0];
      zr1[g] = hi ? t3 : a[g][1];
    }
    float xlo[4], xhi[4];
#pragma unroll
    for (int g = 0; g < 4; ++g) {
      xlo[g] = __uint_as_float(xc[g] << 16);
      xhi[g] = __uint_as_float(xc[g] & 0xffff0000u);
    }
    float h0, h1;
    {
      float ig = sig_(zr0[0] + xlo[0]), fg = sig_(zr0[1] + xlo[1]);
      float gv = tanh_(zr0[2] + xlo[2]), og = sig_(zr0[3] + xlo[3]);
      c0 = fmaf(fg, c0, ig * gv);
      h0 = og * tanh_(c0);
    }
    {
      float ig = sig_(zr1[0] + xhi[0]), fg = sig_(zr1[1] + xhi[1]);
      float gv = tanh_(zr1[2] + xhi[2]), og = sig_(zr1[3] + xhi[3]);
      c1 = fmaf(fg, c1, ig * gv);
      h1 = og * tanh_(c1);
    }
    unsigned hp = pack2(h0, h1);
    *(unsigned*)&WB[sLoc * 136 + up] = hp;                      // h -> HT[nxt]
    *(unsigned*)(obase + (size_t)tphys * 256) = hp;             // h -> global
  };

  for (int t = 0; t < kS; t += 2) {
    int ta = rev ? 511 - t : t;
    int tb = rev ? 510 - t : t + 1;
    int pa = (t + 2 < kS) ? t + 2 : kS - 1;
    int pb = (t + 3 < kS) ? t + 3 : kS - 1;
    int tpa = rev ? 511 - pa : pa;
    int tpb = rev ? 511 - pb : pb;
    do_step(ta, tpa, &HT[0][0][0], &HT[1][0][0], xA);
    __syncthreads();
    do_step(tb, tpb, &HT[1][0][0], &HT[0][0][0], xB);
    __syncthreads();
  }
}

// ---------------------------------------------------------------------------
// K6: classifier + char mask. out1 bf16 -> em fp32 (or NEG)
// ---------------------------------------------------------------------------
__global__ __launch_bounds__(256) void k_cls(
    const bf16* __restrict__ out1, const float* __restrict__ cls_w,
    const float* __restrict__ cls_b, const int* __restrict__ x,
    float* __restrict__ em) {
  __shared__ float W[17 * 256];
  __shared__ float part[64 * 4 * 17];
  int tid = threadIdx.x;
  for (int i = tid; i < 17 * 256; i += 256) W[i] = cls_w[i];
  __syncthreads();
  int r = tid >> 2, q = tid & 3;
  size_t row = (size_t)blockIdx.x * 64 + r;
  float acc[17];
#pragma unroll
  for (int j = 0; j < 17; ++j) acc[j] = 0.f;
  const uint4* a4p = (const uint4*)(out1 + row * 256 + q * 64);
  for (int i = 0; i < 8; ++i) {
    float f8[8]; unpack8(a4p[i], f8);
#pragma unroll
    for (int j = 0; j < 17; ++j) {
      const float* wr = &W[j * 256 + q * 64 + i * 8];
#pragma unroll
      for (int e = 0; e < 8; ++e) acc[j] = fmaf(f8[e], wr[e], acc[j]);
    }
  }
#pragma unroll
  for (int j = 0; j < 17; ++j) part[(r * 4 + q) * 17 + j] = acc[j];
  __syncthreads();
  for (int idx = tid; idx < 64 * 17; idx += 256) {
    int rr = idx / 17, j = idx % 17;
    size_t row2 = (size_t)blockIdx.x * 64 + rr;
    float v = part[(rr * 4 + 0) * 17 + j] + part[(rr * 4 + 1) * 17 + j] +
              part[(rr * 4 + 2) * 17 + j] + part[(rr * 4 + 3) * 17 + j] + cls_b[j];
    em[row2 * 17 + j] = (x[row2] != 0) ? v : -1e9f;
  }
}

// ---------------------------------------------------------------------------
// K7: CRF loss per sequence (1 wave / block). res[b] = logZ - score
// ---------------------------------------------------------------------------
__global__ __launch_bounds__(64) void k_crf(
    const float* __restrict__ em, const int* __restrict__ tags,
    const float* __restrict__ mask, const float* __restrict__ trans,
    const float* __restrict__ start_t, const float* __restrict__ end_t,
    float* __restrict__ res) {
  int b = blockIdx.x;
  int lane = threadIdx.x;
  const float* emB = em + (size_t)b * kS * 17;
  const int* tg = tags + b * kS;
  const float* mk = mask + b * kS;

  float tcol[17];
  if (lane < 17) {
#pragma unroll
    for (int i = 0; i < 17; ++i) tcol[i] = trans[i * 17 + lane];
  }
  float sc = 0.f, msum = 0.f;
  for (int t = lane; t < kS; t += 64) msum += mk[t];
  for (int t = 1 + lane; t < kS; t += 64)
    sc += (trans[tg[t - 1] * 17 + tg[t]] + emB[(size_t)t * 17 + tg[t]]) * mk[t];
#pragma unroll
  for (int o = 32; o; o >>= 1) { sc += __shfl_xor(sc, o); msum += __shfl_xor(msum, o); }

  __shared__ float al[17];
  if (lane < 17) al[lane] = start_t[lane] + emB[lane];
  __syncthreads();
  for (int t = 1; t < kS; ++t) {
    float nxt = 0.f;
    if (lane < 17) {
      float v[17]; float mx = -3.4e38f;
#pragma unroll
      for (int i = 0; i < 17; ++i) { v[i] = al[i] + tcol[i]; mx = fmaxf(mx, v[i]); }
      float s = 0.f;
#pragma unroll
      for (int i = 0; i < 17; ++i) s += __expf(v[i] - mx);
      float m = mk[t];
      nxt = (mx + __logf(s) + emB[(size_t)t * 17 + lane]) * m + al[lane] * (1.f - m);
    }
    __syncthreads();
    if (lane < 17) al[lane] = nxt;
    __syncthreads();
  }
  float val = (lane < 17) ? al[lane] + end_t[lane] : -3.4e38f;
  float mx = val;
#pragma unroll
  for (int o = 32; o; o >>= 1) mx = fmaxf(mx, __shfl_xor(mx, o));
  float s = (lane < 17) ? __expf(val - mx) : 0.f;
#pragma unroll
  for (int o = 32; o; o >>= 1) s += __shfl_xor(s, o);
  float logZ = mx + __logf(s);
  if (lane == 0) {
    float score = sc + start_t[tg[0]] + emB[tg[0]];
    int last_real = (int)(msum + 0.5f) - 1;
    if (last_real >= 0) score += end_t[tg[last_real]];
    res[b] = logZ - score;
  }
}

// K8: deterministic mean over 128 sequences -> d_out[0]
__global__ void k_loss(const float* __restrict__ res, float* __restrict__ out) {
  __shared__ float s[128];
  int tid = threadIdx.x;
  s[tid] = res[tid];
  __syncthreads();
  for (int off = 64; off; off >>= 1) {
    if (tid < off) s[tid] += s[tid + off];
    __syncthreads();
  }
  if (tid == 0) out[0] = s[0] / 128.f;
}

}  // namespace

extern "C" void kernel_launch(void* const* d_in, const int* in_sizes, int n_in,
                              void* d_out, int out_size, void* d_ws, size_t ws_size,
                              hipStream_t stream) {
  (void)in_sizes; (void)n_in; (void)out_size; (void)ws_size;
  const int*   x       = (const int*)  d_in[0];
  const int*   tags    = (const int*)  d_in[1];
  const float* mask    = (const float*)d_in[2];
  const float* emb     = (const float*)d_in[3];
  const float* cw3     = (const float*)d_in[4];
  const float* cb3     = (const float*)d_in[5];
  const float* cw5     = (const float*)d_in[6];
  const float* cb5     = (const float*)d_in[7];
  const float* cw7     = (const float*)d_in[8];
  const float* cb7     = (const float*)d_in[9];
  const float* hw_w    = (const float*)d_in[10];
  const float* hw_b    = (const float*)d_in[11];
  const float* hwg_w   = (const float*)d_in[12];
  const float* hwg_b   = (const float*)d_in[13];
  const float* wih0f   = (const float*)d_in[14];
  const float* whh0f   = (const float*)d_in[15];
  const float* b0f     = (const float*)d_in[16];
  const float* wih0b   = (const float*)d_in[17];
  const float* whh0b   = (const float*)d_in[18];
  const float* b0b     = (const float*)d_in[19];
  const float* wih1f   = (const float*)d_in[20];
  const float* whh1f   = (const float*)d_in[21];
  const float* b1f     = (const float*)d_in[22];
  const float* wih1b   = (const float*)d_in[23];
  const float* whh1b   = (const float*)d_in[24];
  const float* b1b     = (const float*)d_in[25];
  const float* cls_w   = (const float*)d_in[26];
  const float* cls_b   = (const float*)d_in[27];
  const float* trans   = (const float*)d_in[28];
  const float* start_t = (const float*)d_in[29];
  const float* end_t   = (const float*)d_in[30];

  // Workspace layout. tbl fp32 | bf16 weights | bf16 activations. ~210 MB.
  char* ws = (char*)d_ws;
  const size_t OFF_W0 = 393216;                            // tbl is [0, 372KB)
  const size_t OFF_W1 = OFF_W0 + (size_t)1024 * 192 * 2;
  const size_t OFF_WA = OFF_W1 + (size_t)1024 * 256 * 2;
  const size_t OFF_WG = OFF_WA + (size_t)192 * 192 * 2;
  const size_t OFF_WH = OFF_WG + (size_t)192 * 192 * 2;    // 4x whh bf16 (512KB)
  const size_t OFF_A  = OFF_WH + (size_t)4 * 512 * 128 * 2;
  const size_t SZ_A   = (size_t)kM * 192 * 2;              // 24 MB
  const size_t OFF_B  = OFF_A + SZ_A;
  const size_t OFF_O0 = OFF_B + SZ_A;                      // out0 bf16 (32MB); em fp32 later
  const size_t OFF_XG = OFF_O0 + (size_t)kM * 256 * 2;     // xg bf16 dual (128MB)
  float* tbl  = (float*)ws;
  bf16*  W0b  = (bf16*)(ws + OFF_W0);
  bf16*  W1b  = (bf16*)(ws + OFF_W1);
  bf16*  WAb  = (bf16*)(ws + OFF_WA);
  bf16*  WGb  = (bf16*)(ws + OFF_WG);
  bf16*  WHb  = (bf16*)(ws + OFF_WH);
  bf16*  bufA = (bf16*)(ws + OFF_A);
  bf16*  bufB = (bf16*)(ws + OFF_B);
  bf16*  out0 = (bf16*)(ws + OFF_O0);
  bf16*  out1 = (bf16*)(ws + OFF_A);                       // bufA/bufB dead by rec1
  bf16*  xg   = (bf16*)(ws + OFF_XG);
  float* em   = (float*)(ws + OFF_O0);                     // out0 dead after proj1
  float* resv = (float*)(ws + OFF_O0 + (size_t)kM * 17 * 4);

  // weight conversion prepass
  k_w2b<<<384, 256, 0, stream>>>(wih0f, W0b, 512 * 192);
  k_w2b<<<384, 256, 0, stream>>>(wih0b, W0b + 512 * 192, 512 * 192);
  k_w2b<<<512, 256, 0, stream>>>(wih1f, W1b, 512 * 256);
  k_w2b<<<512, 256, 0, stream>>>(wih1b, W1b + 512 * 256, 512 * 256);
  k_w2b<<<144, 256, 0, stream>>>(hw_w, WAb, 192 * 192);
  k_w2b<<<144, 256, 0, stream>>>(hwg_w, WGb, 192 * 192);
  k_w2b<<<256, 256, 0, stream>>>(whh0f, WHb + 0 * 65536, 512 * 128);
  k_w2b<<<256, 256, 0, stream>>>(whh0b, WHb + 1 * 65536, 512 * 128);
  k_w2b<<<256, 256, 0, stream>>>(whh1f, WHb + 2 * 65536, 512 * 128);
  k_w2b<<<256, 256, 0, stream>>>(whh1b, WHb + 3 * 65536, 512 * 128);

  k_table<<<15 * 97, 64, 0, stream>>>(emb, cw3, cw5, cw7, tbl);
  k_conv<<<kB * (kS / 64), 192, 0, stream>>>(x, tbl, cb3, cb5, cb7, bufA);
  k_hw<<<dim3(kM / 128, 3), 256, 0, stream>>>(bufA, WAb, hw_b, WGb, hwg_b, bufB);

  k_pgemm<<<dim3(kM / 128, 8), 256, 0, stream>>>(bufB, 192, W0b, b0f, b0b, xg);
  k_rec2<<<32, 512, 0, stream>>>(xg, WHb + 0 * 65536, WHb + 1 * 65536, out0);
  k_pgemm<<<dim3(kM / 128, 8), 256, 0, stream>>>(out0, 256, W1b, b1f, b1b, xg);
  k_rec2<<<32, 512, 0, stream>>>(xg, WHb + 2 * 65536, WHb + 3 * 65536, out1);

  k_cls<<<kM / 64, 256, 0, stream>>>(out1, cls_w, cls_b, x, em);
  k_crf<<<kB, 64, 0, stream>>>(em, tags, mask, trans, start_t, end_t, resv);
  k_loss<<<1, 128, 0, stream>>>(resv, (float*)d_out);
}